// Round 1
// baseline (1709.334 us; speedup 1.0000x reference)
//
#include <hip/hip_runtime.h>

#define N_NODES 100000
#define N_EDGES 1600000

// ---------------- workspace layout (floats) ----------------
// 0      : m      (N)   segment-max as monotone-uint (init 0)
// N      : s      (N)   softmax denom
// 2N     : hagg1  (8N)  softmax-weighted agg of encoder feats
// 10N    : agg1   (N)   edge-MLP sum, round 1
// 11N    : agg2   (N)   edge-MLP sum, round 2
// 12N    : hagg2  (8N)  final weighted agg
// 20N    : h_enc  (8N)
// 28N    : h_r1   (8N)
// 36N    : h_r2   (8N)
// 44N    : wbuf   (E)   exp() then normalized softmax weight
// 44N+E  : he1    (E)
// 44N+2E : he2    (E)

__global__ void zero_kernel(float* p, int n) {
    int i = blockIdx.x * blockDim.x + threadIdx.x;
    int stride = gridDim.x * blockDim.x;
    for (; i < n; i += stride) p[i] = 0.f;
}

__global__ void seg_max_kernel(const float* __restrict__ dist, const int* __restrict__ dst,
                               unsigned* __restrict__ m, int E) {
    int e = blockIdx.x * blockDim.x + threadIdx.x;
    if (e >= E) return;
    unsigned raw = __float_as_uint(dist[e]);
    unsigned mono = (raw & 0x80000000u) ? ~raw : (raw | 0x80000000u);
    atomicMax(m + dst[e], mono);
}

__global__ void exp_sum_kernel(const float* __restrict__ dist, const int* __restrict__ dst,
                               const unsigned* __restrict__ m, float* __restrict__ s,
                               float* __restrict__ wbuf, int E) {
    int e = blockIdx.x * blockDim.x + threadIdx.x;
    if (e >= E) return;
    int d = dst[e];
    unsigned mono = m[d];
    unsigned raw = (mono & 0x80000000u) ? (mono & 0x7FFFFFFFu) : ~mono;
    float mx = __uint_as_float(raw);
    float v = expf(dist[e] - mx);
    wbuf[e] = v;
    atomicAdd(s + d, v);
}

// one thread per (edge, channel); 8 channels
template <bool NORM>
__global__ void agg_kernel(float* wbuf, const float* __restrict__ s,
                           const float* __restrict__ hfeat,
                           const int* __restrict__ src, const int* __restrict__ dst,
                           float* __restrict__ out, int E) {
    int t = blockIdx.x * blockDim.x + threadIdx.x;
    if (t >= E * 8) return;
    int e = t >> 3, c = t & 7;
    float w = wbuf[e];
    int d = dst[e];
    if (NORM) {
        w = w / s[d];
        // all 8 lanes of this edge-group read wbuf[e] in lockstep (same wave)
        // before this store executes, so in-place normalize is safe.
        if (c == 0) wbuf[e] = w;
    }
    atomicAdd(out + d * 8 + c, w * hfeat[src[e] * 8 + c]);
}

// ---------------- per-wave node MLP: DIN -> 64 -> 64 -> DOUT (all relu) -----
// wave = one node; lane j owns hidden unit j (weight columns in registers)
template <int CA, int CB, int DOUT>
__global__ __launch_bounds__(256) void node_mlp_kernel(
    const float* __restrict__ xa, const float* __restrict__ xb,
    const float* __restrict__ w1, const float* __restrict__ b1,
    const float* __restrict__ w2, const float* __restrict__ b2,
    const float* __restrict__ w3, const float* __restrict__ b3,
    float* __restrict__ out, int n) {
    constexpr int DIN = CA + CB;
    __shared__ float hs[4][64];
    __shared__ float w3s[64 * DOUT + DOUT];
    int lane = threadIdx.x & 63, wid = threadIdx.x >> 6;
    for (int i = threadIdx.x; i < 64 * DOUT; i += 256) w3s[i] = w3[i];
    if (threadIdx.x < DOUT) w3s[64 * DOUT + threadIdx.x] = b3[threadIdx.x];
    float w1c[DIN];
#pragma unroll
    for (int k = 0; k < DIN; ++k) w1c[k] = w1[k * 64 + lane];
    float b1r = b1[lane];
    float w2c[64];
#pragma unroll
    for (int k = 0; k < 64; ++k) w2c[k] = w2[k * 64 + lane];
    float b2r = b2[lane];
    __syncthreads();

    int wavesTotal = gridDim.x * 4;
    int iters = (n + wavesTotal - 1) / wavesTotal;
    int wgid = blockIdx.x * 4 + wid;
    for (int it = 0; it < iters; ++it) {
        int node = wgid + it * wavesTotal;
        bool valid = node < n;
        float x[DIN];
        if (valid) {
#pragma unroll
            for (int k = 0; k < CA; ++k) x[k] = xa[node * CA + k];
#pragma unroll
            for (int k = 0; k < CB; ++k) x[CA + k] = xb[node * CB + k];
        } else {
#pragma unroll
            for (int k = 0; k < DIN; ++k) x[k] = 0.f;
        }
        float h1 = b1r;
#pragma unroll
        for (int k = 0; k < DIN; ++k) h1 = fmaf(x[k], w1c[k], h1);
        h1 = fmaxf(h1, 0.f);
        __syncthreads();   // WAR vs previous iteration's reads
        hs[wid][lane] = h1;
        __syncthreads();
        float h2 = b2r;
#pragma unroll
        for (int k = 0; k < 64; k += 4) {
            float4 hv = *(const float4*)&hs[wid][k];
            h2 = fmaf(hv.x, w2c[k], h2);
            h2 = fmaf(hv.y, w2c[k + 1], h2);
            h2 = fmaf(hv.z, w2c[k + 2], h2);
            h2 = fmaf(hv.w, w2c[k + 3], h2);
        }
        h2 = fmaxf(h2, 0.f);
        __syncthreads();
        hs[wid][lane] = h2;
        __syncthreads();
        int o = lane % DOUT, seg = lane / DOUT;
        float p = 0.f;
#pragma unroll
        for (int j = 0; j < DOUT; ++j) {
            int k = seg * DOUT + j;
            p += hs[wid][k] * w3s[k * DOUT + o];
        }
#pragma unroll
        for (int off = DOUT; off < 64; off <<= 1) p += __shfl_xor(p, off, 64);
        if (valid && lane < DOUT) out[node * DOUT + o] = fmaxf(p + w3s[64 * DOUT + o], 0.f);
    }
}

// ---------------- per-wave edge MLP: 17 -> 64 -> 64 -> 1 (all relu) ---------
__global__ __launch_bounds__(256) void edge_mlp_kernel(
    const float* __restrict__ he_in, const float* __restrict__ h,
    const int* __restrict__ src, const int* __restrict__ dst,
    const float* __restrict__ w1, const float* __restrict__ b1,
    const float* __restrict__ w2, const float* __restrict__ b2,
    const float* __restrict__ w3, const float* __restrict__ b3,
    float* __restrict__ he_out, float* __restrict__ agg, int E) {
    __shared__ float hs[4][64];
    int lane = threadIdx.x & 63, wid = threadIdx.x >> 6;
    float w1c[17];
#pragma unroll
    for (int k = 0; k < 17; ++k) w1c[k] = w1[k * 64 + lane];
    float b1r = b1[lane];
    float w2c[64];
#pragma unroll
    for (int k = 0; k < 64; ++k) w2c[k] = w2[k * 64 + lane];
    float b2r = b2[lane];
    float w3r = w3[lane];
    float b3r = b3[0];

    int wavesTotal = gridDim.x * 4;
    int iters = (E + wavesTotal - 1) / wavesTotal;
    int wgid = blockIdx.x * 4 + wid;
    for (int it = 0; it < iters; ++it) {
        int e = wgid + it * wavesTotal;
        bool valid = e < E;
        float x[17];
        int d = 0;
        if (valid) {
            d = dst[e];
            int sr = src[e];
            x[0] = he_in[e];
            float4 a0 = *(const float4*)(h + sr * 8);
            float4 a1 = *(const float4*)(h + sr * 8 + 4);
            float4 d0 = *(const float4*)(h + d * 8);
            float4 d1 = *(const float4*)(h + d * 8 + 4);
            x[1] = a0.x;  x[2] = a0.y;  x[3] = a0.z;  x[4] = a0.w;
            x[5] = a1.x;  x[6] = a1.y;  x[7] = a1.z;  x[8] = a1.w;
            x[9] = d0.x;  x[10] = d0.y; x[11] = d0.z; x[12] = d0.w;
            x[13] = d1.x; x[14] = d1.y; x[15] = d1.z; x[16] = d1.w;
        } else {
#pragma unroll
            for (int k = 0; k < 17; ++k) x[k] = 0.f;
        }
        float h1 = b1r;
#pragma unroll
        for (int k = 0; k < 17; ++k) h1 = fmaf(x[k], w1c[k], h1);
        h1 = fmaxf(h1, 0.f);
        __syncthreads();   // WAR vs previous iteration's reads
        hs[wid][lane] = h1;
        __syncthreads();
        float h2 = b2r;
#pragma unroll
        for (int k = 0; k < 64; k += 4) {
            float4 hv = *(const float4*)&hs[wid][k];
            h2 = fmaf(hv.x, w2c[k], h2);
            h2 = fmaf(hv.y, w2c[k + 1], h2);
            h2 = fmaf(hv.z, w2c[k + 2], h2);
            h2 = fmaf(hv.w, w2c[k + 3], h2);
        }
        h2 = fmaxf(h2, 0.f);
        float p = h2 * w3r;
#pragma unroll
        for (int off = 32; off; off >>= 1) p += __shfl_xor(p, off, 64);
        if (valid && lane == 0) {
            float o = fmaxf(p + b3r, 0.f);
            he_out[e] = o;
            atomicAdd(agg + d, o);
        }
    }
}

extern "C" void kernel_launch(void* const* d_in, const int* in_sizes, int n_in,
                              void* d_out, int out_size, void* d_ws, size_t ws_size,
                              hipStream_t stream) {
    const int N = N_NODES, E = N_EDGES;
    const float* node_feat = (const float*)d_in[0];
    const float* edge_feat = (const float*)d_in[1];
    const float* edge_dist = (const float*)d_in[2];
    const int* src = (const int*)d_in[3];
    const int* dst = (const int*)d_in[4];
    const float* w_enc1 = (const float*)d_in[5];  const float* b_enc1 = (const float*)d_in[6];
    const float* w_enc2 = (const float*)d_in[7];  const float* b_enc2 = (const float*)d_in[8];
    const float* w_enc3 = (const float*)d_in[9];  const float* b_enc3 = (const float*)d_in[10];
    const float* w_dec1 = (const float*)d_in[11]; const float* b_dec1 = (const float*)d_in[12];
    const float* w_dec2 = (const float*)d_in[13]; const float* b_dec2 = (const float*)d_in[14];
    const float* w_dec3 = (const float*)d_in[15]; const float* b_dec3 = (const float*)d_in[16];
    const float* w_nod1 = (const float*)d_in[17]; const float* b_nod1 = (const float*)d_in[18];
    const float* w_nod2 = (const float*)d_in[19]; const float* b_nod2 = (const float*)d_in[20];
    const float* w_nod3 = (const float*)d_in[21]; const float* b_nod3 = (const float*)d_in[22];
    const float* w_edg1 = (const float*)d_in[23]; const float* b_edg1 = (const float*)d_in[24];
    const float* w_edg2 = (const float*)d_in[25]; const float* b_edg2 = (const float*)d_in[26];
    const float* w_edg3 = (const float*)d_in[27]; const float* b_edg3 = (const float*)d_in[28];

    float* ws = (float*)d_ws;
    unsigned* m   = (unsigned*)ws;
    float* s      = ws + N;
    float* hagg1  = ws + 2 * N;
    float* agg1   = ws + 10 * N;
    float* agg2   = ws + 11 * N;
    float* hagg2  = ws + 12 * N;
    float* h_enc  = ws + 20 * N;
    float* h_r1   = ws + 28 * N;
    float* h_r2   = ws + 36 * N;
    float* wbuf   = ws + 44 * N;
    float* he1    = wbuf + E;
    float* he2    = he1 + E;

    // zero all accumulators (m's zero == monotone "-inf")
    zero_kernel<<<2048, 256, 0, stream>>>(ws, 20 * N);
    // encoder
    node_mlp_kernel<3, 0, 8><<<2048, 256, 0, stream>>>(node_feat, nullptr,
        w_enc1, b_enc1, w_enc2, b_enc2, w_enc3, b_enc3, h_enc, N);
    // edge softmax
    seg_max_kernel<<<(E + 255) / 256, 256, 0, stream>>>(edge_dist, dst, m, E);
    exp_sum_kernel<<<(E + 255) / 256, 256, 0, stream>>>(edge_dist, dst, m, s, wbuf, E);
    // normalize + first weighted aggregation
    agg_kernel<true><<<(E * 8 + 255) / 256, 256, 0, stream>>>(wbuf, s, h_enc, src, dst, hagg1, E);
    // round 1
    edge_mlp_kernel<<<2048, 256, 0, stream>>>(edge_feat, hagg1, src, dst,
        w_edg1, b_edg1, w_edg2, b_edg2, w_edg3, b_edg3, he1, agg1, E);
    node_mlp_kernel<1, 8, 8><<<2048, 256, 0, stream>>>(agg1, hagg1,
        w_nod1, b_nod1, w_nod2, b_nod2, w_nod3, b_nod3, h_r1, N);
    // round 2
    edge_mlp_kernel<<<2048, 256, 0, stream>>>(he1, h_r1, src, dst,
        w_edg1, b_edg1, w_edg2, b_edg2, w_edg3, b_edg3, he2, agg2, E);
    node_mlp_kernel<1, 8, 8><<<2048, 256, 0, stream>>>(agg2, h_r1,
        w_nod1, b_nod1, w_nod2, b_nod2, w_nod3, b_nod3, h_r2, N);
    // second weighted aggregation (reuses normalized wbuf)
    agg_kernel<false><<<(E * 8 + 255) / 256, 256, 0, stream>>>(wbuf, s, h_r2, src, dst, hagg2, E);
    // decoder -> output
    node_mlp_kernel<8, 0, 1><<<2048, 256, 0, stream>>>(hagg2, nullptr,
        w_dec1, b_dec1, w_dec2, b_dec2, w_dec3, b_dec3, (float*)d_out, N);
}

// Round 3
// 1239.976 us; speedup vs baseline: 1.3785x; 1.3785x over previous
//
#include <hip/hip_runtime.h>

#define N_NODES 100000
#define N_EDGES 1600000

// ---------------- workspace layout (floats) ----------------
// 0      : m      (N)   segment-max as monotone-uint (init 0)
// N      : s      (N)   softmax denom
// 2N     : hagg1  (8N)  softmax-weighted agg of encoder feats
// 10N    : agg1   (N)   edge-MLP sum, round 1
// 11N    : agg2   (N)   edge-MLP sum, round 2
// 12N    : hagg2  (8N)  final weighted agg
// 20N    : h_enc  (8N)
// 28N    : h_r1   (8N)
// 36N    : h_r2   (8N)
// 44N    : wbuf   (E)   exp() then normalized softmax weight
// 44N+E  : he1    (E)
// 44N+2E : he2    (E)

__global__ void zero_kernel(float* p, int n) {
    int i = blockIdx.x * blockDim.x + threadIdx.x;
    int stride = gridDim.x * blockDim.x;
    for (; i < n; i += stride) p[i] = 0.f;
}

__global__ void seg_max_kernel(const float* __restrict__ dist, const int* __restrict__ dst,
                               unsigned* __restrict__ m, int E) {
    int e = blockIdx.x * blockDim.x + threadIdx.x;
    if (e >= E) return;
    unsigned raw = __float_as_uint(dist[e]);
    unsigned mono = (raw & 0x80000000u) ? ~raw : (raw | 0x80000000u);
    atomicMax(m + dst[e], mono);
}

__global__ void exp_sum_kernel(const float* __restrict__ dist, const int* __restrict__ dst,
                               const unsigned* __restrict__ m, float* __restrict__ s,
                               float* __restrict__ wbuf, int E) {
    int e = blockIdx.x * blockDim.x + threadIdx.x;
    if (e >= E) return;
    int d = dst[e];
    unsigned mono = m[d];
    unsigned raw = (mono & 0x80000000u) ? (mono & 0x7FFFFFFFu) : ~mono;
    float mx = __uint_as_float(raw);
    float v = expf(dist[e] - mx);
    wbuf[e] = v;
    atomicAdd(s + d, v);
}

// one thread per (edge, channel); 8 channels
template <bool NORM>
__global__ void agg_kernel(float* wbuf, const float* __restrict__ s,
                           const float* __restrict__ hfeat,
                           const int* __restrict__ src, const int* __restrict__ dst,
                           float* __restrict__ out, int E) {
    int t = blockIdx.x * blockDim.x + threadIdx.x;
    if (t >= E * 8) return;
    int e = t >> 3, c = t & 7;
    float w = wbuf[e];
    int d = dst[e];
    if (NORM) {
        w = w / s[d];
        // all 8 lanes of this edge-group read wbuf[e] in lockstep (same wave)
        // before this store executes, so in-place normalize is safe.
        if (c == 0) wbuf[e] = w;
    }
    atomicAdd(out + d * 8 + c, w * hfeat[src[e] * 8 + c]);
}

// ---------------- thread-per-item fused MLP: DIN -> 64 -> 64 -> DOUT --------
// Each thread runs the whole MLP for one item. All weight/bias indices are
// wave-uniform -> compiler emits s_load; every v_fmac has an SGPR operand,
// so each VALU instruction performs 64 useful lane-MACs. No LDS, no barriers,
// no shuffles. h1[64] is statically indexed everywhere (k-loop fully
// unrolled inside the dynamic jb-loop) so it stays in VGPRs.
template <int DIN, int DOUT>
__device__ __forceinline__ void mlp_64_64(
    const float* __restrict__ x,
    const float* __restrict__ w1, const float* __restrict__ b1,
    const float* __restrict__ w2, const float* __restrict__ b2,
    const float* __restrict__ w3, const float* __restrict__ b3,
    float* __restrict__ out) {
    float h1[64];
#pragma unroll
    for (int j = 0; j < 64; ++j) {
        float a = b1[j];
#pragma unroll
        for (int k = 0; k < DIN; ++k) a = fmaf(x[k], w1[k * 64 + j], a);
        h1[j] = fmaxf(a, 0.f);
    }
    float acc[DOUT];
#pragma unroll
    for (int o = 0; o < DOUT; ++o) acc[o] = b3[o];
    for (int jb = 0; jb < 64; jb += 8) {  // dynamic loop: 8 iters, uniform jb
        float h2[8];
#pragma unroll
        for (int u = 0; u < 8; ++u) h2[u] = b2[jb + u];
#pragma unroll
        for (int k = 0; k < 64; ++k) {    // static: h1[k] stays in registers
            float h1k = h1[k];
#pragma unroll
            for (int u = 0; u < 8; ++u)
                h2[u] = fmaf(h1k, w2[k * 64 + jb + u], h2[u]);
        }
#pragma unroll
        for (int u = 0; u < 8; ++u) {
            float r = fmaxf(h2[u], 0.f);
#pragma unroll
            for (int o = 0; o < DOUT; ++o)
                acc[o] = fmaf(r, w3[(jb + u) * DOUT + o], acc[o]);
        }
    }
#pragma unroll
    for (int o = 0; o < DOUT; ++o) out[o] = fmaxf(acc[o], 0.f);
}

// thread-per-node MLP: x = concat(xa[CA], xb[CB]) -> DOUT
template <int CA, int CB, int DOUT>
__global__ __launch_bounds__(256) void node_mlp_kernel(
    const float* __restrict__ xa, const float* __restrict__ xb,
    const float* __restrict__ w1, const float* __restrict__ b1,
    const float* __restrict__ w2, const float* __restrict__ b2,
    const float* __restrict__ w3, const float* __restrict__ b3,
    float* __restrict__ out, int n) {
    constexpr int DIN = CA + CB;
    int i = blockIdx.x * 256 + threadIdx.x;
    if (i >= n) return;
    float x[DIN];
#pragma unroll
    for (int k = 0; k < CA; ++k) x[k] = xa[i * CA + k];
    if (CB == 8) {
        float4 v0 = *(const float4*)(xb + i * 8);
        float4 v1 = *(const float4*)(xb + i * 8 + 4);
        x[CA + 0] = v0.x; x[CA + 1] = v0.y; x[CA + 2] = v0.z; x[CA + 3] = v0.w;
        x[CA + 4] = v1.x; x[CA + 5] = v1.y; x[CA + 6] = v1.z; x[CA + 7] = v1.w;
    }
    float o[DOUT];
    mlp_64_64<DIN, DOUT>(x, w1, b1, w2, b2, w3, b3, o);
#pragma unroll
    for (int k = 0; k < DOUT; ++k) out[i * DOUT + k] = o[k];
}

// thread-per-edge MLP: 17 -> 64 -> 64 -> 1, plus segment-sum into agg[dst]
__global__ __launch_bounds__(256) void edge_mlp_kernel(
    const float* __restrict__ he_in, const float* __restrict__ h,
    const int* __restrict__ src, const int* __restrict__ dst,
    const float* __restrict__ w1, const float* __restrict__ b1,
    const float* __restrict__ w2, const float* __restrict__ b2,
    const float* __restrict__ w3, const float* __restrict__ b3,
    float* __restrict__ he_out, float* __restrict__ agg, int E) {
    int e = blockIdx.x * 256 + threadIdx.x;
    if (e >= E) return;
    int d = dst[e], sr = src[e];
    float x[17];
    x[0] = he_in[e];
    float4 a0 = *(const float4*)(h + sr * 8);
    float4 a1 = *(const float4*)(h + sr * 8 + 4);
    float4 d0 = *(const float4*)(h + d * 8);
    float4 d1 = *(const float4*)(h + d * 8 + 4);
    x[1] = a0.x;  x[2] = a0.y;  x[3] = a0.z;  x[4] = a0.w;
    x[5] = a1.x;  x[6] = a1.y;  x[7] = a1.z;  x[8] = a1.w;
    x[9] = d0.x;  x[10] = d0.y; x[11] = d0.z; x[12] = d0.w;
    x[13] = d1.x; x[14] = d1.y; x[15] = d1.z; x[16] = d1.w;
    float o;
    mlp_64_64<17, 1>(x, w1, b1, w2, b2, w3, b3, &o);
    he_out[e] = o;
    atomicAdd(agg + d, o);
}

extern "C" void kernel_launch(void* const* d_in, const int* in_sizes, int n_in,
                              void* d_out, int out_size, void* d_ws, size_t ws_size,
                              hipStream_t stream) {
    const int N = N_NODES, E = N_EDGES;
    const float* node_feat = (const float*)d_in[0];
    const float* edge_feat = (const float*)d_in[1];
    const float* edge_dist = (const float*)d_in[2];
    const int* src = (const int*)d_in[3];
    const int* dst = (const int*)d_in[4];
    const float* w_enc1 = (const float*)d_in[5];  const float* b_enc1 = (const float*)d_in[6];
    const float* w_enc2 = (const float*)d_in[7];  const float* b_enc2 = (const float*)d_in[8];
    const float* w_enc3 = (const float*)d_in[9];  const float* b_enc3 = (const float*)d_in[10];
    const float* w_dec1 = (const float*)d_in[11]; const float* b_dec1 = (const float*)d_in[12];
    const float* w_dec2 = (const float*)d_in[13]; const float* b_dec2 = (const float*)d_in[14];
    const float* w_dec3 = (const float*)d_in[15]; const float* b_dec3 = (const float*)d_in[16];
    const float* w_nod1 = (const float*)d_in[17]; const float* b_nod1 = (const float*)d_in[18];
    const float* w_nod2 = (const float*)d_in[19]; const float* b_nod2 = (const float*)d_in[20];
    const float* w_nod3 = (const float*)d_in[21]; const float* b_nod3 = (const float*)d_in[22];
    const float* w_edg1 = (const float*)d_in[23]; const float* b_edg1 = (const float*)d_in[24];
    const float* w_edg2 = (const float*)d_in[25]; const float* b_edg2 = (const float*)d_in[26];
    const float* w_edg3 = (const float*)d_in[27]; const float* b_edg3 = (const float*)d_in[28];

    float* ws = (float*)d_ws;
    unsigned* m   = (unsigned*)ws;
    float* s      = ws + N;
    float* hagg1  = ws + 2 * N;
    float* agg1   = ws + 10 * N;
    float* agg2   = ws + 11 * N;
    float* hagg2  = ws + 12 * N;
    float* h_enc  = ws + 20 * N;
    float* h_r1   = ws + 28 * N;
    float* h_r2   = ws + 36 * N;
    float* wbuf   = ws + 44 * N;
    float* he1    = wbuf + E;
    float* he2    = he1 + E;

    // zero all accumulators (m's zero == monotone "-inf")
    zero_kernel<<<2048, 256, 0, stream>>>(ws, 20 * N);
    // encoder
    node_mlp_kernel<3, 0, 8><<<(N + 255) / 256, 256, 0, stream>>>(node_feat, nullptr,
        w_enc1, b_enc1, w_enc2, b_enc2, w_enc3, b_enc3, h_enc, N);
    // edge softmax
    seg_max_kernel<<<(E + 255) / 256, 256, 0, stream>>>(edge_dist, dst, m, E);
    exp_sum_kernel<<<(E + 255) / 256, 256, 0, stream>>>(edge_dist, dst, m, s, wbuf, E);
    // normalize + first weighted aggregation
    agg_kernel<true><<<(E * 8 + 255) / 256, 256, 0, stream>>>(wbuf, s, h_enc, src, dst, hagg1, E);
    // round 1
    edge_mlp_kernel<<<(E + 255) / 256, 256, 0, stream>>>(edge_feat, hagg1, src, dst,
        w_edg1, b_edg1, w_edg2, b_edg2, w_edg3, b_edg3, he1, agg1, E);
    node_mlp_kernel<1, 8, 8><<<(N + 255) / 256, 256, 0, stream>>>(agg1, hagg1,
        w_nod1, b_nod1, w_nod2, b_nod2, w_nod3, b_nod3, h_r1, N);
    // round 2
    edge_mlp_kernel<<<(E + 255) / 256, 256, 0, stream>>>(he1, h_r1, src, dst,
        w_edg1, b_edg1, w_edg2, b_edg2, w_edg3, b_edg3, he2, agg2, E);
    node_mlp_kernel<1, 8, 8><<<(N + 255) / 256, 256, 0, stream>>>(agg2, h_r1,
        w_nod1, b_nod1, w_nod2, b_nod2, w_nod3, b_nod3, h_r2, N);
    // second weighted aggregation (reuses normalized wbuf)
    agg_kernel<false><<<(E * 8 + 255) / 256, 256, 0, stream>>>(wbuf, s, h_r2, src, dst, hagg2, E);
    // decoder -> output
    node_mlp_kernel<8, 0, 1><<<(N + 255) / 256, 256, 0, stream>>>(hagg2, nullptr,
        w_dec1, b_dec1, w_dec2, b_dec2, w_dec3, b_dec3, (float*)d_out, N);
}

// Round 4
// 896.522 us; speedup vs baseline: 1.9066x; 1.3831x over previous
//
#include <hip/hip_runtime.h>

#define N_NODES 100000
#define N_EDGES 1600000

// ---------------- workspace layout (floats) ----------------
// 0      : m      (N)   segment-max as monotone-uint (init 0)
// N      : s      (N)   softmax denom
// 2N     : hagg1  (8N)
// 10N    : agg1   (N)
// 11N    : agg2   (N)
// 12N    : hagg2  (8N)
// 20N    : h_enc  (8N)
// 28N    : h_r1   (8N)
// 36N    : h_r2   (8N)
// 44N    : wbuf   (E)
// 44N+E  : he1    (E)
// 44N+2E : he2    (E)
// 44N+3E : packed weights (enc 64*80, nod 64*80, edg 64*96, dec 64*80)

__global__ void zero_kernel(float* p, int n) {
    int i = blockIdx.x * blockDim.x + threadIdx.x;
    int stride = gridDim.x * blockDim.x;
    for (; i < n; i += stride) p[i] = 0.f;
}

__global__ void seg_max_kernel(const float* __restrict__ dist, const int* __restrict__ dst,
                               unsigned* __restrict__ m, int E) {
    int e = blockIdx.x * blockDim.x + threadIdx.x;
    if (e >= E) return;
    unsigned raw = __float_as_uint(dist[e]);
    unsigned mono = (raw & 0x80000000u) ? ~raw : (raw | 0x80000000u);
    atomicMax(m + dst[e], mono);
}

__global__ void exp_sum_kernel(const float* __restrict__ dist, const int* __restrict__ dst,
                               const unsigned* __restrict__ m, float* __restrict__ s,
                               float* __restrict__ wbuf, int E) {
    int e = blockIdx.x * blockDim.x + threadIdx.x;
    if (e >= E) return;
    int d = dst[e];
    unsigned mono = m[d];
    unsigned raw = (mono & 0x80000000u) ? (mono & 0x7FFFFFFFu) : ~mono;
    float mx = __uint_as_float(raw);
    float v = expf(dist[e] - mx);
    wbuf[e] = v;
    atomicAdd(s + d, v);
}

// one thread per (edge, channel); 8 channels
template <bool NORM>
__global__ void agg_kernel(float* wbuf, const float* __restrict__ s,
                           const float* __restrict__ hfeat,
                           const int* __restrict__ src, const int* __restrict__ dst,
                           float* __restrict__ out, int E) {
    int t = blockIdx.x * blockDim.x + threadIdx.x;
    if (t >= E * 8) return;
    int e = t >> 3, c = t & 7;
    float w = wbuf[e];
    int d = dst[e];
    if (NORM) {
        w = w / s[d];
        // all 8 lanes of this edge-group read wbuf[e] in lockstep (same wave)
        // before this store executes, so in-place normalize is safe.
        if (c == 0) wbuf[e] = w;
    }
    atomicAdd(out + d * 8 + c, w * hfeat[src[e] * 8 + c]);
}

// ---------------- weight packing -------------------------------------------
// Per-k row (k = hidden-1 unit): [0..63] = w2[k,:]  (16B*4 aligned chunks)
//                                [64..64+DIN-1] = w1[:,k] (column)
//                                [64+DIN] = b1[k]
struct PackArgs { const float *w1, *b1, *w2; float* out; int din, stride; };

__global__ void pack_kernel(PackArgs a0, PackArgs a1, PackArgs a2, PackArgs a3) {
    PackArgs a = (blockIdx.x == 0) ? a0 : (blockIdx.x == 1) ? a1
               : (blockIdx.x == 2) ? a2 : a3;
    int k = threadIdx.x;  // 64 threads
    float* row = a.out + k * a.stride;
    for (int j = 0; j < 64; ++j) row[j] = a.w2[k * 64 + j];
    for (int j = 0; j < a.din; ++j) row[64 + j] = a.w1[j * 64 + k];
    row[64 + a.din] = a.b1[k];
}

// ---------------- loop-swapped fused MLP: DIN -> 64 -> 64 -> DOUT ----------
// For each hidden-1 unit k: compute h1k (DIN FMAs), then rank-1 update of
// h2[64]. h1 is never materialized; live state = x[DIN] + h2[64] -> fits in
// arch VGPRs under __launch_bounds__(256,4) (cap 128). All weight addresses
// are wave-uniform -> s_load_dwordx16 into SGPRs; every hot VALU op is a
// v_fmac with an SGPR operand. Accumulation order identical to reference
// (k ascending, j ascending).
template <int DIN, int DOUT, int STRIDE>
__device__ __forceinline__ void mlp_fused(
    const float* __restrict__ x, const float* __restrict__ wp,
    const float* __restrict__ b2,
    const float* __restrict__ w3, const float* __restrict__ b3,
    float* __restrict__ out) {
    float h2[64];
#pragma unroll
    for (int j = 0; j < 64; ++j) h2[j] = b2[j];
    for (int k = 0; k < 64; ++k) {          // dynamic: uniform trip, low I-cache
        const float* row = wp + k * STRIDE;
        float a = row[64 + DIN];            // b1[k]
#pragma unroll
        for (int j = 0; j < DIN; ++j) a = fmaf(x[j], row[64 + j], a);
        a = fmaxf(a, 0.f);
#pragma unroll
        for (int j = 0; j < 64; ++j) h2[j] = fmaf(a, row[j], h2[j]);
    }
    float acc[DOUT];
#pragma unroll
    for (int o = 0; o < DOUT; ++o) acc[o] = b3[o];
#pragma unroll
    for (int j = 0; j < 64; ++j) {
        float r = fmaxf(h2[j], 0.f);
#pragma unroll
        for (int o = 0; o < DOUT; ++o) acc[o] = fmaf(r, w3[j * DOUT + o], acc[o]);
    }
#pragma unroll
    for (int o = 0; o < DOUT; ++o) out[o] = fmaxf(acc[o], 0.f);
}

// thread-per-node MLP: x = concat(xa[CA], xb[CB]) -> DOUT
template <int CA, int CB, int DOUT, int STRIDE>
__global__ __launch_bounds__(256, 4) void node_mlp_kernel(
    const float* __restrict__ xa, const float* __restrict__ xb,
    const float* __restrict__ wp, const float* __restrict__ b2,
    const float* __restrict__ w3, const float* __restrict__ b3,
    float* __restrict__ out, int n) {
    constexpr int DIN = CA + CB;
    int i = blockIdx.x * 256 + threadIdx.x;
    if (i >= n) return;
    float x[DIN];
#pragma unroll
    for (int k = 0; k < CA; ++k) x[k] = xa[i * CA + k];
    if (CB == 8) {
        float4 v0 = *(const float4*)(xb + i * 8);
        float4 v1 = *(const float4*)(xb + i * 8 + 4);
        x[CA + 0] = v0.x; x[CA + 1] = v0.y; x[CA + 2] = v0.z; x[CA + 3] = v0.w;
        x[CA + 4] = v1.x; x[CA + 5] = v1.y; x[CA + 6] = v1.z; x[CA + 7] = v1.w;
    }
    float o[DOUT];
    mlp_fused<DIN, DOUT, STRIDE>(x, wp, b2, w3, b3, o);
#pragma unroll
    for (int k = 0; k < DOUT; ++k) out[i * DOUT + k] = o[k];
}

// thread-per-edge MLP: 17 -> 64 -> 64 -> 1, plus segment-sum into agg[dst]
__global__ __launch_bounds__(256, 4) void edge_mlp_kernel(
    const float* __restrict__ he_in, const float* __restrict__ h,
    const int* __restrict__ src, const int* __restrict__ dst,
    const float* __restrict__ wp, const float* __restrict__ b2,
    const float* __restrict__ w3, const float* __restrict__ b3,
    float* __restrict__ he_out, float* __restrict__ agg, int E) {
    int e = blockIdx.x * 256 + threadIdx.x;
    if (e >= E) return;
    int d = dst[e], sr = src[e];
    float x[17];
    x[0] = he_in[e];
    float4 a0 = *(const float4*)(h + sr * 8);
    float4 a1 = *(const float4*)(h + sr * 8 + 4);
    float4 d0 = *(const float4*)(h + d * 8);
    float4 d1 = *(const float4*)(h + d * 8 + 4);
    x[1] = a0.x;  x[2] = a0.y;  x[3] = a0.z;  x[4] = a0.w;
    x[5] = a1.x;  x[6] = a1.y;  x[7] = a1.z;  x[8] = a1.w;
    x[9] = d0.x;  x[10] = d0.y; x[11] = d0.z; x[12] = d0.w;
    x[13] = d1.x; x[14] = d1.y; x[15] = d1.z; x[16] = d1.w;
    float o;
    mlp_fused<17, 1, 96>(x, wp, b2, w3, b3, &o);
    he_out[e] = o;
    atomicAdd(agg + d, o);
}

extern "C" void kernel_launch(void* const* d_in, const int* in_sizes, int n_in,
                              void* d_out, int out_size, void* d_ws, size_t ws_size,
                              hipStream_t stream) {
    const int N = N_NODES, E = N_EDGES;
    const float* node_feat = (const float*)d_in[0];
    const float* edge_feat = (const float*)d_in[1];
    const float* edge_dist = (const float*)d_in[2];
    const int* src = (const int*)d_in[3];
    const int* dst = (const int*)d_in[4];
    const float* w_enc1 = (const float*)d_in[5];  const float* b_enc1 = (const float*)d_in[6];
    const float* w_enc2 = (const float*)d_in[7];  const float* b_enc2 = (const float*)d_in[8];
    const float* w_enc3 = (const float*)d_in[9];  const float* b_enc3 = (const float*)d_in[10];
    const float* w_dec1 = (const float*)d_in[11]; const float* b_dec1 = (const float*)d_in[12];
    const float* w_dec2 = (const float*)d_in[13]; const float* b_dec2 = (const float*)d_in[14];
    const float* w_dec3 = (const float*)d_in[15]; const float* b_dec3 = (const float*)d_in[16];
    const float* w_nod1 = (const float*)d_in[17]; const float* b_nod1 = (const float*)d_in[18];
    const float* w_nod2 = (const float*)d_in[19]; const float* b_nod2 = (const float*)d_in[20];
    const float* w_nod3 = (const float*)d_in[21]; const float* b_nod3 = (const float*)d_in[22];
    const float* w_edg1 = (const float*)d_in[23]; const float* b_edg1 = (const float*)d_in[24];
    const float* w_edg2 = (const float*)d_in[25]; const float* b_edg2 = (const float*)d_in[26];
    const float* w_edg3 = (const float*)d_in[27]; const float* b_edg3 = (const float*)d_in[28];

    float* ws = (float*)d_ws;
    unsigned* m   = (unsigned*)ws;
    float* s      = ws + N;
    float* hagg1  = ws + 2 * N;
    float* agg1   = ws + 10 * N;
    float* agg2   = ws + 11 * N;
    float* hagg2  = ws + 12 * N;
    float* h_enc  = ws + 20 * N;
    float* h_r1   = ws + 28 * N;
    float* h_r2   = ws + 36 * N;
    float* wbuf   = ws + 44 * N;
    float* he1    = wbuf + E;
    float* he2    = he1 + E;
    float* pk_enc = he2 + E;            // 64*80
    float* pk_nod = pk_enc + 64 * 80;   // 64*80
    float* pk_edg = pk_nod + 64 * 80;   // 64*96
    float* pk_dec = pk_edg + 64 * 96;   // 64*80

    // pack weights (runs every call; weights are restored by harness)
    PackArgs pa0{w_enc1, b_enc1, w_enc2, pk_enc, 3, 80};
    PackArgs pa1{w_nod1, b_nod1, w_nod2, pk_nod, 9, 80};
    PackArgs pa2{w_edg1, b_edg1, w_edg2, pk_edg, 17, 96};
    PackArgs pa3{w_dec1, b_dec1, w_dec2, pk_dec, 8, 80};
    pack_kernel<<<4, 64, 0, stream>>>(pa0, pa1, pa2, pa3);

    // zero all accumulators (m's zero == monotone "-inf")
    zero_kernel<<<2048, 256, 0, stream>>>(ws, 20 * N);
    // encoder
    node_mlp_kernel<3, 0, 8, 80><<<(N + 255) / 256, 256, 0, stream>>>(node_feat, nullptr,
        pk_enc, b_enc2, w_enc3, b_enc3, h_enc, N);
    // edge softmax
    seg_max_kernel<<<(E + 255) / 256, 256, 0, stream>>>(edge_dist, dst, m, E);
    exp_sum_kernel<<<(E + 255) / 256, 256, 0, stream>>>(edge_dist, dst, m, s, wbuf, E);
    // normalize + first weighted aggregation
    agg_kernel<true><<<(E * 8 + 255) / 256, 256, 0, stream>>>(wbuf, s, h_enc, src, dst, hagg1, E);
    // round 1
    edge_mlp_kernel<<<(E + 255) / 256, 256, 0, stream>>>(edge_feat, hagg1, src, dst,
        pk_edg, b_edg2, w_edg3, b_edg3, he1, agg1, E);
    node_mlp_kernel<1, 8, 8, 80><<<(N + 255) / 256, 256, 0, stream>>>(agg1, hagg1,
        pk_nod, b_nod2, w_nod3, b_nod3, h_r1, N);
    // round 2
    edge_mlp_kernel<<<(E + 255) / 256, 256, 0, stream>>>(he1, h_r1, src, dst,
        pk_edg, b_edg2, w_edg3, b_edg3, he2, agg2, E);
    node_mlp_kernel<1, 8, 8, 80><<<(N + 255) / 256, 256, 0, stream>>>(agg2, h_r1,
        pk_nod, b_nod2, w_nod3, b_nod3, h_r2, N);
    // second weighted aggregation (reuses normalized wbuf)
    agg_kernel<false><<<(E * 8 + 255) / 256, 256, 0, stream>>>(wbuf, s, h_r2, src, dst, hagg2, E);
    // decoder -> output
    node_mlp_kernel<8, 0, 1, 80><<<(N + 255) / 256, 256, 0, stream>>>(hagg2, nullptr,
        pk_dec, b_dec2, w_dec3, b_dec3, (float*)d_out, N);
}